// Round 1
// baseline (940.038 us; speedup 1.0000x reference)
//
#include <hip/hip_runtime.h>

// FDTD wave-equation rollout, temporally blocked.
// Grid 512x512, `steps` frames produced (steps = out_size / (512*512)).
// Each launch advances TS=16 steps inside LDS per 32x32 output tile
// (64x64 halo-extended region), writing every intermediate frame.

#define HH 512
#define WW 512
#define TILE 32
#define TS 16
#define EXT 64          // TILE + 2*TS
#define LDW 65          // padded leading dim (bank-conflict safety)

// f32 constant matching JAX's fold of 2.0*3.1415926*100.0 (double) -> f32
#define PHC ((float)(2.0 * 3.1415926 * 100.0))

__global__ __launch_bounds__(256)
void fdtd_tb_kernel(const float* __restrict__ prevF,   // frame F(t0)
                    const float* __restrict__ curF,    // frame F(t0+1)
                    const float* __restrict__ cmap,    // c, [512*512]
                    const int* __restrict__ locx,
                    const int* __restrict__ locy,
                    const int* __restrict__ pb,        // bsize1
                    const int* __restrict__ pid2,      // id2
                    float* __restrict__ out,           // all output planes
                    int t0, int nk)
{
    __shared__ float sA[EXT][LDW];
    __shared__ float sB[EXT][LDW];
    __shared__ float sC[EXT][LDW];

    const int tid = threadIdx.x;
    const int bx = blockIdx.x & 15;        // tile col index (W/TILE = 16)
    const int by = blockIdx.x >> 4;        // tile row index
    const int gx0 = bx * TILE - TS;        // global col of local col 0
    const int gy0 = by * TILE - TS;        // global row of local row 0

    const int col  = tid & 63;             // load/compute column (0..63)
    const int row0 = tid >> 6;             // 0..3

    // ---- load extended region (prev, cur, c) ----
    {
        const int gc = gx0 + col;
        if (gc >= 0 && gc < WW) {
            #pragma unroll
            for (int m = 0; m < 16; ++m) {
                const int r = row0 + 4 * m;
                const int gr = gy0 + r;
                if (gr >= 0 && gr < HH) {
                    const int gidx = gr * WW + gc;
                    sA[r][col] = prevF[gidx];
                    sB[r][col] = curF[gidx];
                    sC[r][col] = cmap[gidx];
                }
            }
        }
    }

    const int lx0 = locx[0], ly0 = locy[0];
    const int lx1 = locx[1], ly1 = locy[1];
    const int lx2 = locx[2], ly2 = locy[2];
    const int Bn  = pb[0] * pid2[0];

    __syncthreads();

    float (*pP)[LDW] = sA;   // holds "prev" frame; new frame written in place
    float (*pC)[LDW] = sB;   // holds "cur" frame

    const int gc = gx0 + col;

    for (int k = 1; k <= nk; ++k) {
        // source value for output plane t = t0+k-1  (scan n = t+1)
        const float srcv =
            1500.0f * sinf(PHC * (float)(Bn + t0 + k + 1) * 1.0e-4f);

        // valid local rect at step k: [k, 63-k] clipped to physical domain
        const int rlo = max(k, -gy0), rhi = min(63 - k, 511 - gy0);
        const int clo = max(k, -gx0), chi = min(63 - k, 511 - gx0);

        if (col >= clo && col <= chi) {
            for (int m = 0; m < 16; ++m) {
                const int r = row0 + 4 * m;
                if (r < rlo || r > rhi) continue;
                const int gr = gy0 + r;
                const float cv  = sC[r][col];
                const float cen = pC[r][col];
                float val;
                // boundary precedence (last torch write wins):
                // row511 > col511 > col0 > row0 > source > interior
                if (gr == HH - 1) {
                    val = cen - 1.0e-4f * cv * (cen - pC[r - 1][col]);
                } else if (gc == WW - 1) {
                    val = cen - 1.0e-4f * cv * (cen - pC[r][col - 1]);
                } else if (gc == 0) {
                    val = cen - 1.0e-4f * cv * (cen - pC[r][col + 1]);
                } else if (gr == 0) {
                    val = cen - 1.0e-4f * cv * (cen - pC[r + 1][col]);
                } else {
                    const float rr  = 1.0e-8f * cv * cv;
                    const float lap = rr *
                        ((pC[r + 1][col] - 2.0f * cen + pC[r - 1][col]) +
                         (pC[r][col + 1] - 2.0f * cen + pC[r][col - 1]));
                    val = 2.0f * cen - pP[r][col] + lap;
                    if ((gr == lx0 && gc == ly0) ||
                        (gr == lx1 && gc == ly1) ||
                        (gr == lx2 && gc == ly2))
                        val = srcv;
                }
                pP[r][col] = val;
            }
        }

        __syncthreads();

        // swap: pC now holds the new frame
        float (*t_)[LDW] = pP; pP = pC; pC = t_;

        // write output plane t0+k-1 (32x32 tile, local [16..47]^2)
        {
            float* op = out + (size_t)(t0 + k - 1) * (HH * WW);
            const int oc  = 16 + (tid & 31);
            const int or0 = 16 + (tid >> 5);   // 16..23
            #pragma unroll
            for (int m = 0; m < 4; ++m) {
                const int r = or0 + 8 * m;
                op[(gy0 + r) * WW + (gx0 + oc)] = pC[r][oc];
            }
        }
        // no barrier needed here: next compute writes the OTHER buffer and
        // reads pP center only at same-thread-owned cells
    }
}

extern "C" void kernel_launch(void* const* d_in, const int* in_sizes, int n_in,
                              void* d_out, int out_size, void* d_ws, size_t ws_size,
                              hipStream_t stream) {
    const float* in_out = (const float*)d_in[0];   // [steps+2, 1, 512, 512]
    const float* cmap   = (const float*)d_in[1];   // [1,1,512,512]
    const int*   locx   = (const int*)d_in[2];
    const int*   locy   = (const int*)d_in[3];
    const int*   pb     = (const int*)d_in[4];     // bsize1
    const int*   pid2   = (const int*)d_in[5];     // id2
    float* out = (float*)d_out;

    const int HW = HH * WW;
    const int steps = out_size / HW;
    const int nblocks = (HH / TILE) * (WW / TILE); // 256

    for (int t0 = 0; t0 < steps; t0 += TS) {
        const int nk = (steps - t0 < TS) ? (steps - t0) : TS;
        const float *prevF, *curF;
        if (t0 == 0) {
            prevF = in_out;            // F(0) = output[0,0]
            curF  = in_out + HW;       // F(1) = output[1,0]
        } else {
            prevF = out + (size_t)(t0 - 2) * HW;  // F(t0)
            curF  = out + (size_t)(t0 - 1) * HW;  // F(t0+1)
        }
        hipLaunchKernelGGL(fdtd_tb_kernel, dim3(nblocks), dim3(256), 0, stream,
                           prevF, curF, cmap, locx, locy, pb, pid2, out, t0, nk);
    }
}

// Round 2
// 403.417 us; speedup vs baseline: 2.3302x; 2.3302x over previous
//
#include <hip/hip_runtime.h>

// FDTD wave-equation rollout, temporally blocked, register-resident state.
// 512x512 grid; each launch advances TS=16 steps per 32x32 output tile
// using a 64x64 halo region. Only `cur` lives in LDS (double-buffered);
// prev / center / c / r-coeff / source-mask are per-thread registers.

#define HH 512
#define WW 512
#define TILE 32
#define TS 16
#define EXT 64
#define LDW 65
#define PHC ((float)(2.0 * 3.1415926 * 100.0))

__global__ __launch_bounds__(1024)
void fdtd_tb2(const float* __restrict__ prevF,
              const float* __restrict__ curF,
              const float* __restrict__ cmap,
              const int* __restrict__ locx,
              const int* __restrict__ locy,
              const int* __restrict__ pb,
              const int* __restrict__ pid2,
              float* __restrict__ out,
              int t0, int nk)
{
    __shared__ float sA[EXT][LDW];
    __shared__ float sB[EXT][LDW];

    const int tid  = threadIdx.x;
    const int bx   = blockIdx.x & 15;
    const int by   = blockIdx.x >> 4;
    const int gx0  = bx * TILE - TS;
    const int gy0  = by * TILE - TS;
    const int col  = tid & 63;          // local column 0..63 (lane)
    const int rowg = tid >> 6;          // 0..15; rows rowg+16m, m=0..3
    const int gc   = gx0 + col;

    const int lx0 = locx[0], ly0 = locy[0];
    const int lx1 = locx[1], ly1 = locy[1];
    const int lx2 = locx[2], ly2 = locy[2];
    const int Bn  = pb[0] * pid2[0];

    float cen[4], pv[4], rr[4], cv[4];
    bool  issrc[4];

    #pragma unroll
    for (int m = 0; m < 4; ++m) {
        const int r  = rowg + 16 * m;
        const int gr = gy0 + r;
        float cc = 0.f, ce = 0.f, pp = 0.f;
        if (gr >= 0 && gr < HH && gc >= 0 && gc < WW) {
            const int gi = gr * WW + gc;
            cc = cmap[gi]; ce = curF[gi]; pp = prevF[gi];
        }
        sA[r][col] = ce;
        cen[m] = ce; pv[m] = pp;
        cv[m] = cc;  rr[m] = 1.0e-8f * cc * cc;
        issrc[m] = (gr == lx0 && gc == ly0) || (gr == lx1 && gc == ly1) ||
                   (gr == lx2 && gc == ly2);
    }
    __syncthreads();

    float (*pC)[LDW] = sA;
    float (*pN)[LDW] = sB;
    const bool edge = (bx == 0) | (bx == 15) | (by == 0) | (by == 15);

    if (!edge) {
        // -------- interior blocks: pure stencil, no boundary compares ------
        for (int k = 1; k <= nk; ++k) {
            const float srcv =
                1500.0f * sinf(PHC * (float)(Bn + t0 + k + 1) * 1.0e-4f);
            const int lo = k, hi = 63 - k;
            const bool colok = (col >= lo) & (col <= hi);
            #pragma unroll
            for (int m = 0; m < 4; ++m) {
                const int r = rowg + 16 * m;
                if (colok & (r >= lo) & (r <= hi)) {
                    const float c0 = cen[m];
                    const float lap = rr[m] *
                        ((pC[r + 1][col] - 2.f * c0 + pC[r - 1][col]) +
                         (pC[r][col + 1] - 2.f * c0 + pC[r][col - 1]));
                    float val = 2.f * c0 - pv[m] + lap;
                    if (issrc[m]) val = srcv;
                    pN[r][col] = val;
                    pv[m]  = c0;
                    cen[m] = val;
                }
            }
            __syncthreads();
            // write output plane t0+k-1 straight from registers
            float* op = out + (size_t)(t0 + k - 1) * (HH * WW);
            if (col >= 16 && col <= 47) {
                op[(gy0 + rowg + 16) * WW + gc] = cen[1];
                op[(gy0 + rowg + 32) * WW + gc] = cen[2];
            }
            float (*tmp)[LDW] = pC; pC = pN; pN = tmp;
        }
    } else {
        // -------- edge blocks: clipped rect + boundary formulas ------------
        for (int k = 1; k <= nk; ++k) {
            const float srcv =
                1500.0f * sinf(PHC * (float)(Bn + t0 + k + 1) * 1.0e-4f);
            const int rlo = max(k, -gy0), rhi = min(63 - k, 511 - gy0);
            const int clo = max(k, -gx0), chi = min(63 - k, 511 - gx0);
            const bool colok = (col >= clo) & (col <= chi);
            #pragma unroll
            for (int m = 0; m < 4; ++m) {
                const int r  = rowg + 16 * m;
                const int gr = gy0 + r;
                if (colok & (r >= rlo) & (r <= rhi)) {
                    const float c0 = cen[m];
                    float val;
                    // precedence: row511 > col511 > col0 > row0 > src > interior
                    if (gr == HH - 1) {
                        val = c0 - 1.0e-4f * cv[m] * (c0 - pC[r - 1][col]);
                    } else if (gc == WW - 1) {
                        val = c0 - 1.0e-4f * cv[m] * (c0 - pC[r][col - 1]);
                    } else if (gc == 0) {
                        val = c0 - 1.0e-4f * cv[m] * (c0 - pC[r][col + 1]);
                    } else if (gr == 0) {
                        val = c0 - 1.0e-4f * cv[m] * (c0 - pC[r + 1][col]);
                    } else {
                        const float lap = rr[m] *
                            ((pC[r + 1][col] - 2.f * c0 + pC[r - 1][col]) +
                             (pC[r][col + 1] - 2.f * c0 + pC[r][col - 1]));
                        val = 2.f * c0 - pv[m] + lap;
                        if (issrc[m]) val = srcv;
                    }
                    pN[r][col] = val;
                    pv[m]  = c0;
                    cen[m] = val;
                }
            }
            __syncthreads();
            float* op = out + (size_t)(t0 + k - 1) * (HH * WW);
            if (col >= 16 && col <= 47) {
                op[(gy0 + rowg + 16) * WW + gc] = cen[1];
                op[(gy0 + rowg + 32) * WW + gc] = cen[2];
            }
            float (*tmp)[LDW] = pC; pC = pN; pN = tmp;
        }
    }
}

extern "C" void kernel_launch(void* const* d_in, const int* in_sizes, int n_in,
                              void* d_out, int out_size, void* d_ws, size_t ws_size,
                              hipStream_t stream) {
    const float* in_out = (const float*)d_in[0];   // [steps+2, 1, 512, 512]
    const float* cmap   = (const float*)d_in[1];   // [1,1,512,512]
    const int*   locx   = (const int*)d_in[2];
    const int*   locy   = (const int*)d_in[3];
    const int*   pb     = (const int*)d_in[4];     // bsize1
    const int*   pid2   = (const int*)d_in[5];     // id2
    float* out = (float*)d_out;

    const int HW = HH * WW;
    const int steps = out_size / HW;
    const int nblocks = (HH / TILE) * (WW / TILE); // 256

    for (int t0 = 0; t0 < steps; t0 += TS) {
        const int nk = (steps - t0 < TS) ? (steps - t0) : TS;
        const float *prevF, *curF;
        if (t0 == 0) {
            prevF = in_out;
            curF  = in_out + HW;
        } else {
            prevF = out + (size_t)(t0 - 2) * HW;
            curF  = out + (size_t)(t0 - 1) * HW;
        }
        hipLaunchKernelGGL(fdtd_tb2, dim3(nblocks), dim3(1024), 0, stream,
                           prevF, curF, cmap, locx, locy, pb, pid2, out, t0, nk);
    }
}

// Round 3
// 248.413 us; speedup vs baseline: 3.7842x; 1.6240x over previous
//
#include <hip/hip_runtime.h>

// FDTD rollout, temporally blocked (TS=16 steps/launch), register-resident
// state, float4-vectorized LDS traffic. 512x512 grid, 256 blocks x 1024 thr;
// each block owns a 32x32 output tile via a 64x64 halo region in LDS.
// Thread layout: 64 rows x 16 col-groups; each thread = 1 row x 4 cols.

#define HH 512
#define WW 512
#define TILE 32
#define TS 16
#define EXT 64
#define LDW 68   // row stride 272 B (16B-aligned), padding cols 64..67 zeroed
#define PHC ((float)(2.0 * 3.1415926 * 100.0))

typedef float f4 __attribute__((ext_vector_type(4)));

__global__ __launch_bounds__(1024)
void fdtd_tb3(const float* __restrict__ prevF,
              const float* __restrict__ curF,
              const float* __restrict__ cmap,
              const int* __restrict__ locx,
              const int* __restrict__ locy,
              const int* __restrict__ pb,
              const int* __restrict__ pid2,
              float* __restrict__ out,
              int t0, int nk)
{
    __shared__ float sA[EXT * LDW];
    __shared__ float sB[EXT * LDW];

    const int tid = threadIdx.x;
    const int bx  = blockIdx.x & 15;
    const int by  = blockIdx.x >> 4;
    const int gx0 = bx * TILE - TS;
    const int gy0 = by * TILE - TS;

    const int cg  = tid & 15;       // column group 0..15
    const int r   = tid >> 4;       // local row 0..63
    const int c0  = cg * 4;         // local col of lane's first cell
    const int gr  = gy0 + r;
    const int gc0 = gx0 + c0;

    // clamped LDS element offsets (clamps only matter for garbage cells)
    const int rm = (r == 0)  ? 0  : r - 1;
    const int rp = (r == 63) ? 63 : r + 1;
    const int oU = rm * LDW + c0;
    const int oD = rp * LDW + c0;
    const int oL = r * LDW + ((c0 == 0) ? 0 : c0 - 1);
    const int oR = r * LDW + c0 + 4;
    const int oC = r * LDW + c0;

    const int lx0 = locx[0], ly0 = locy[0];
    const int lx1 = locx[1], ly1 = locy[1];
    const int lx2 = locx[2], ly2 = locy[2];
    const int Bn  = pb[0] * pid2[0];

    // ---- initial load: float4 per thread per array ----
    f4 cen = {0.f, 0.f, 0.f, 0.f}, pv = cen, cc = cen;
    const bool inb = (gr >= 0) & (gr < HH) & (gc0 >= 0) & (gc0 < WW);
    if (inb) {
        const int gi = gr * WW + gc0;
        cen = *(const f4*)(curF + gi);
        pv  = *(const f4*)(prevF + gi);
        cc  = *(const f4*)(cmap + gi);
    }
    *(f4*)(sA + oC) = cen;
    if (cg == 15) {                 // zero padding cols so no NaN enters
        const int pz = r * LDW + 64;
        #pragma unroll
        for (int j = 0; j < 4; ++j) { sA[pz + j] = 0.f; sB[pz + j] = 0.f; }
    }

    f4 rr, cv = cc;
    #pragma unroll
    for (int j = 0; j < 4; ++j) rr[j] = 1.0e-8f * cc[j] * cc[j];

    bool issrc[4];
    #pragma unroll
    for (int j = 0; j < 4; ++j) {
        const int gcj = gc0 + j;
        issrc[j] = (gr == lx0 && gcj == ly0) || (gr == lx1 && gcj == ly1) ||
                   (gr == lx2 && gcj == ly2);
    }

    const bool doStore = (r >= 16) & (r <= 47) & (cg >= 4) & (cg <= 11);
    const bool edge = (bx == 0) | (bx == 15) | (by == 0) | (by == 15);

    __syncthreads();

    float* pC = sA;
    float* pN = sB;

    if (!edge) {
        // ---------------- interior blocks: branch-free stencil -------------
        for (int k = 1; k <= nk; ++k) {
            const float srcv =
                1500.0f * sinf(PHC * (float)(Bn + t0 + k + 1) * 1.0e-4f);
            const f4 up = *(const f4*)(pC + oU);
            const f4 dn = *(const f4*)(pC + oD);
            const float lf = pC[oL];
            const float rt = pC[oR];
            const float lN[4] = { lf, cen[0], cen[1], cen[2] };
            const float rN[4] = { cen[1], cen[2], cen[3], rt };
            f4 val;
            #pragma unroll
            for (int j = 0; j < 4; ++j) {
                const float c = cen[j];
                const float lap = rr[j] * ((up[j] - 2.f * c + dn[j]) +
                                           (rN[j] - 2.f * c + lN[j]));
                float v = 2.f * c - pv[j] + lap;
                val[j] = issrc[j] ? srcv : v;
            }
            pv = cen; cen = val;
            *(f4*)(pN + oC) = val;
            if (doStore)
                *(f4*)(out + (size_t)(t0 + k - 1) * (HH * WW)
                           + (size_t)(gr * WW + gc0)) = val;
            __syncthreads();
            float* t_ = pC; pC = pN; pN = t_;
        }
    } else {
        // ---------------- edge blocks: predicated boundary overrides -------
        const bool isR0   = (gr == 0);
        const bool isR511 = (gr == HH - 1);
        const bool isC0   = (gc0 == 0);            // affects lane 0
        const bool isC511 = (gc0 + 3 == WW - 1);   // affects lane 3
        for (int k = 1; k <= nk; ++k) {
            const float srcv =
                1500.0f * sinf(PHC * (float)(Bn + t0 + k + 1) * 1.0e-4f);
            const f4 up = *(const f4*)(pC + oU);
            const f4 dn = *(const f4*)(pC + oD);
            const float lf = pC[oL];
            const float rt = pC[oR];
            const float lN[4] = { lf, cen[0], cen[1], cen[2] };
            const float rN[4] = { cen[1], cen[2], cen[3], rt };
            f4 val;
            #pragma unroll
            for (int j = 0; j < 4; ++j) {
                const float c = cen[j];
                const float lap = rr[j] * ((up[j] - 2.f * c + dn[j]) +
                                           (rN[j] - 2.f * c + lN[j]));
                float v = 2.f * c - pv[j] + lap;
                v = issrc[j] ? srcv : v;
                // ascending precedence: row0 < col0 < col511 < row511
                if (isR0)            v = c - 1.0e-4f * cv[j] * (c - dn[j]);
                if (isC0 && j == 0)  v = c - 1.0e-4f * cv[0] * (c - cen[1]);
                if (isC511 && j == 3)v = c - 1.0e-4f * cv[3] * (c - cen[2]);
                if (isR511)          v = c - 1.0e-4f * cv[j] * (c - up[j]);
                val[j] = v;
            }
            pv = cen; cen = val;
            *(f4*)(pN + oC) = val;
            if (doStore)
                *(f4*)(out + (size_t)(t0 + k - 1) * (HH * WW)
                           + (size_t)(gr * WW + gc0)) = val;
            __syncthreads();
            float* t_ = pC; pC = pN; pN = t_;
        }
    }
}

extern "C" void kernel_launch(void* const* d_in, const int* in_sizes, int n_in,
                              void* d_out, int out_size, void* d_ws, size_t ws_size,
                              hipStream_t stream) {
    const float* in_out = (const float*)d_in[0];   // [steps+2, 1, 512, 512]
    const float* cmap   = (const float*)d_in[1];   // [1,1,512,512]
    const int*   locx   = (const int*)d_in[2];
    const int*   locy   = (const int*)d_in[3];
    const int*   pb     = (const int*)d_in[4];     // bsize1
    const int*   pid2   = (const int*)d_in[5];     // id2
    float* out = (float*)d_out;

    const int HW = HH * WW;
    const int steps = out_size / HW;
    const int nblocks = (HH / TILE) * (WW / TILE); // 256

    for (int t0 = 0; t0 < steps; t0 += TS) {
        const int nk = (steps - t0 < TS) ? (steps - t0) : TS;
        const float *prevF, *curF;
        if (t0 == 0) {
            prevF = in_out;
            curF  = in_out + HW;
        } else {
            prevF = out + (size_t)(t0 - 2) * HW;
            curF  = out + (size_t)(t0 - 1) * HW;
        }
        hipLaunchKernelGGL(fdtd_tb3, dim3(nblocks), dim3(1024), 0, stream,
                           prevF, curF, cmap, locx, locy, pb, pid2, out, t0, nk);
    }
}